// Round 10
// baseline (209.250 us; speedup 1.0000x reference)
//
#include <hip/hip_runtime.h>
#include <hip/hip_bf16.h>

// Problem dims (fixed)
#define BB   8
#define LL   32
#define NINV 64
#define NOUTV 16
#define DINV 128
#define EE   64
#define DCV  512

#define EPSF 1e-8f
#define LBDF 1e-3f
// 32 * ln(2*pi)
#define SUM_LN2PI 58.8120661250990508f

typedef float f32x2 __attribute__((ext_vector_type(2)));

static __device__ __forceinline__ f32x2 pkfma(f32x2 a, f32x2 b, f32x2 c) {
    return __builtin_elementwise_fma(a, b, c);   // -> v_pk_fma_f32
}

static __device__ __forceinline__ unsigned int cvt_pk_bf16(float lo, float hi) {
    unsigned int r;
    asm("v_cvt_pk_bf16_f32 %0, %1, %2" : "=v"(r) : "v"(lo), "v"(hi));
    return r;
}

// ---------------------------------------------------------------------------
// Kernel 1 (blocks 0..255): c = ctx@Wc + bc; tc = tanh(c);
//   vbar[e] = tc @ Wv + bv   (n-independent part of votes, EXACT f32)
//   sc[e]   = 1 - tc^2       (sech^2(c) for the Taylor delta-GEMM)
// (blocks 256..263): actn = sigmoid(inu@Wa + ba)
// ---------------------------------------------------------------------------
__global__ __launch_bounds__(64) void prep_kernel(
    const float* __restrict__ ctx, const float* __restrict__ Wc, const float* __restrict__ bc,
    const float* __restrict__ inu, const float* __restrict__ Wa, const float* __restrict__ ba,
    const float* __restrict__ Wv, const float* __restrict__ bv,
    float* __restrict__ vbar_out, float* __restrict__ sc_out, float* __restrict__ actn_out)
{
    const int blk = blockIdx.x;
    const int t = threadIdx.x;
    __shared__ float row[DCV];
    __shared__ float tc_sh[EE];
    if (blk < BB * LL) {
        const float* cr = ctx + (size_t)blk * DCV;
        #pragma unroll
        for (int i = 0; i < DCV / 64; ++i) row[t + 64 * i] = cr[t + 64 * i];
        __syncthreads();
        float acc = bc[t];
        for (int d = 0; d < DCV; ++d) acc = fmaf(row[d], Wc[d * EE + t], acc);
        const float tc = tanhf(acc);
        tc_sh[t] = tc;
        __syncthreads();
        float vb = bv[t];
        #pragma unroll 8
        for (int e1 = 0; e1 < EE; ++e1) vb = fmaf(tc_sh[e1], Wv[e1 * EE + t], vb);
        vbar_out[blk * EE + t] = vb;
        sc_out[blk * EE + t] = fmaf(-tc, tc, 1.0f);
    } else {
        const int b = blk - BB * LL;
        const float* ir = inu + ((size_t)b * NINV + t) * DINV;
        float acc = ba[0];
        for (int d = 0; d < DINV; ++d) acc = fmaf(ir[d], Wa[d], acc);
        actn_out[b * NINV + t] = 1.0f / (1.0f + expf(-acc));
    }
}

// ---------------------------------------------------------------------------
// Kernel 2: block (n,o):
//   priors[b,e] = sum_d inu[b,n,d] * rw[n,o,d,e]   (8x128 @ 128x64)
//   u[b,n,o,e]  = priors[b,:] @ Wu + bu
// ---------------------------------------------------------------------------
__global__ __launch_bounds__(256) void priors_u_kernel(
    const float* __restrict__ inu, const float* __restrict__ rw,
    const float* __restrict__ Wu, const float* __restrict__ bu,
    float* __restrict__ u_out)
{
    const int no = blockIdx.x;      // n*16+o
    const int n  = no >> 4;
    const int oo = no & 15;
    const int tid = threadIdx.x;

    __shared__ float inu_sh[BB * DINV];   // 4 KB
    __shared__ float pri_sh[BB * EE];     // 2 KB

    {   // stage inu[:, n, :]
        const int b = tid >> 5;
        const int i = (tid & 31) * 4;
        const float4 s = *(const float4*)(inu + ((size_t)b * NINV + n) * DINV + i);
        *(float4*)(inu_sh + b * DINV + i) = s;
    }
    __syncthreads();

    const int bg = tid >> 6;   // 0..3 -> handles b = 2bg, 2bg+1
    const int e  = tid & 63;
    const float* rwp = rw + (size_t)no * DINV * EE + e;
    const float* r0 = inu_sh + (bg * 2) * DINV;
    const float* r1 = inu_sh + (bg * 2 + 1) * DINV;
    float a0 = 0.0f, a1 = 0.0f;
    for (int d = 0; d < DINV; ++d) {
        const float w = rwp[d * EE];
        a0 = fmaf(r0[d], w, a0);
        a1 = fmaf(r1[d], w, a1);
    }
    pri_sh[(bg * 2) * EE + e] = a0;
    pri_sh[(bg * 2 + 1) * EE + e] = a1;
    __syncthreads();

    float b0 = bu[e], b1 = b0;
    const float* p0 = pri_sh + (bg * 2) * EE;
    const float* p1 = pri_sh + (bg * 2 + 1) * EE;
    for (int e1 = 0; e1 < EE; ++e1) {
        const float w = Wu[e1 * EE + e];
        b0 = fmaf(p0[e1], w, b0);
        b1 = fmaf(p1[e1], w, b1);
    }
    u_out[(((size_t)(bg * 2) * NINV + n) * NOUTV + oo) * EE + e] = b0;
    u_out[(((size_t)(bg * 2 + 1) * NINV + n) * NOUTV + oo) * EE + e] = b1;
}

// ---------------------------------------------------------------------------
// Kernel 3a: dv GEMM -> global bf16 (pre-swizzled rows).
// dv[R][e] = sum_e1 (u[R,e1]*sc[bl,e1]) * Wv[e1][e], R = bl*1024 + n*16 + o.
// 2048 blocks x 256 threads; wave w: rows blk*128 + (w>>1)*64 + lane,
// e-half = w&1 (Wv half-row address is wave-uniform -> s_load, L1-hot).
// Per-thread state: f32x2 acc[16] (32 VGPR) -- fits the 128-VGPR budget of
// __launch_bounds__(256,4) with slack for load pipelining (round-9's fused
// kernel had 52 VGPR and zero slack -> serialized on load latency).
// Row bytes: chunk kc (8 bf16) stored at ((kc ^ (o&7))*16) -- K3b stages
// linearly and inherits the swizzle.
// ---------------------------------------------------------------------------
__global__ __launch_bounds__(256, 4) void dv_gemm_kernel(
    const float* __restrict__ u_all, const float* __restrict__ sc_all,
    const float* __restrict__ Wv, char* __restrict__ dvg)
{
    const int blk = blockIdx.x;
    const int tid = threadIdx.x;
    const int wave = tid >> 6;
    const int lane = tid & 63;
    const int half = wave & 1;                 // e in [half*32, half*32+32)
    const int R = blk * 128 + (wave >> 1) * 64 + lane;
    const int bl = R >> 10;
    const int rr = R & 1023;                   // n*16 + o
    const int o = R & 15;
    const int b = bl >> 5;

    const float4* u4row = (const float4*)(u_all + ((size_t)b * 1024 + rr) * EE);
    const float* scp = sc_all + bl * EE;       // block-uniform -> s_load

    f32x2 acc[16];
    #pragma unroll
    for (int k = 0; k < 16; ++k) acc[k] = f32x2{0.0f, 0.0f};

    float4 uu = u4row[0];
    for (int c4 = 0; c4 < 16; ++c4) {
        const float4 nxt = (c4 < 15) ? u4row[c4 + 1] : uu;
        #pragma unroll
        for (int j = 0; j < 4; ++j) {
            const int e1 = c4 * 4 + j;
            const float us = ((const float*)&uu)[j] * scp[e1];
            const f32x2 us2 = {us, us};
            const f32x2* w2 = (const f32x2*)(Wv + e1 * EE + half * 32); // wave-uniform
            #pragma unroll
            for (int k = 0; k < 16; ++k) acc[k] = pkfma(us2, w2[k], acc[k]);
        }
        uu = nxt;
    }

    #pragma unroll
    for (int qd = 0; qd < 4; ++qd) {
        uint4 pk;
        pk.x = cvt_pk_bf16(acc[qd * 4 + 0][0], acc[qd * 4 + 0][1]);
        pk.y = cvt_pk_bf16(acc[qd * 4 + 1][0], acc[qd * 4 + 1][1]);
        pk.z = cvt_pk_bf16(acc[qd * 4 + 2][0], acc[qd * 4 + 2][1]);
        pk.w = cvt_pk_bf16(acc[qd * 4 + 3][0], acc[qd * 4 + 3][1]);
        const int kc = half * 4 + qd;
        *(uint4*)(dvg + (size_t)R * 128 + ((kc ^ (o & 7)) * 16)) = pk;
    }
}

// ---------------------------------------------------------------------------
// Kernel 3b: EM only. One 1024-thread block per (b,l); dv staged
// global->LDS once (128 KB, already swizzled); 3 EM iterations on LDS.
// Roles: m-pass 512 threads (o_m, e-pair) sum over n; e-step 1024 threads
// (n,o) read their swizzled row via 8 b128 reads. 2 barriers/iter.
// ---------------------------------------------------------------------------
__global__ __launch_bounds__(1024) void em_kernel(
    const char* __restrict__ dvg, const float* __restrict__ vbar_all,
    const float* __restrict__ actn_all, const unsigned char* __restrict__ mask_all,
    const float* __restrict__ beta_u, const float* __restrict__ beta_a,
    float* __restrict__ out_mu, float* __restrict__ out_r)
{
    const int bl = blockIdx.x;           // 0..255  (= b*32 + l)
    const int b = bl >> 5;
    const int tid = threadIdx.x;
    const int n = tid >> 4;              // e-step role
    const int o = tid & 15;
    const int wid = tid >> 6;
    const int lane = tid & 63;

    __shared__ __align__(16) unsigned int dv_sh[NINV * NOUTV * (EE / 2)]; // 128 KB
    __shared__ __align__(16) float dmu_sh[NOUTV][68];
    __shared__ __align__(16) float q_sh[NOUTV][68];
    __shared__ float ar_sh[NINV][NOUTV];
    __shared__ float actn_sh[NINV];
    __shared__ float vbar_sh[EE];
    __shared__ float sumhl_sh[NOUTV];
    __shared__ float logact_sh[NOUTV];

    char* dvb = (char*)dv_sh;

    // ---- stage dv (this bl's 128 KB) + small vectors ----
    {
        const char* src = dvg + (size_t)bl * 131072 + wid * 8192 + lane * 16;
        char* dst = dvb + wid * 8192 + lane * 16;
        uint4 t0 = *(const uint4*)(src);
        uint4 t1 = *(const uint4*)(src + 1024);
        uint4 t2 = *(const uint4*)(src + 2048);
        uint4 t3 = *(const uint4*)(src + 3072);
        uint4 t4 = *(const uint4*)(src + 4096);
        uint4 t5 = *(const uint4*)(src + 5120);
        uint4 t6 = *(const uint4*)(src + 6144);
        uint4 t7 = *(const uint4*)(src + 7168);
        *(uint4*)(dst)        = t0;
        *(uint4*)(dst + 1024) = t1;
        *(uint4*)(dst + 2048) = t2;
        *(uint4*)(dst + 3072) = t3;
        *(uint4*)(dst + 4096) = t4;
        *(uint4*)(dst + 5120) = t5;
        *(uint4*)(dst + 6144) = t6;
        *(uint4*)(dst + 7168) = t7;
    }
    if (tid < NINV) actn_sh[tid] = actn_all[b * NINV + tid];
    else if (tid < NINV + EE) vbar_sh[tid - NINV] = vbar_all[bl * EE + (tid - NINV)];
    __syncthreads();

    const unsigned char msk = mask_all[b * NINV + n];
    float r_loc = 1.0f / 16.0f;

    for (int it = 0; it < 3; ++it) {
        // ---- ar (normalized over o), write to LDS ----
        float arv = actn_sh[n] * r_loc;
        float s = arv;
        s += __shfl_xor(s, 1, 64);
        s += __shfl_xor(s, 2, 64);
        s += __shfl_xor(s, 4, 64);
        s += __shfl_xor(s, 8, 64);
        arv = arv / (s + EPSF);
        ar_sh[n][o] = arv;
        __syncthreads();                               // B1

        if (it < 2) {
            // ---- m-pass: 512 threads, role (o_m, e-pair); sum over n ----
            if (tid < 512) {
                const int o_m = tid >> 5;
                const int ep = tid & 31;
                const int e0 = ep * 2;
                const char* dvp0 = dvb + o_m * 128 +
                                   (((e0 >> 3) ^ (o_m & 7)) * 16) + ((e0 & 7) >> 1) * 4;
                float S1a = 0.0f, S2a = 0.0f, S1b = 0.0f, S2b = 0.0f, A = 0.0f;
                #pragma unroll 8
                for (int nn = 0; nn < NINV; ++nn) {
                    const float av = ar_sh[nn][o_m];
                    const unsigned int w = *(const unsigned int*)(dvp0 + nn * 2048);
                    const float va = __uint_as_float(w << 16);
                    const float vb = __uint_as_float(w & 0xFFFF0000u);
                    A += av;
                    S1a = fmaf(av, va, S1a);
                    S2a = fmaf(av * va, va, S2a);
                    S1b = fmaf(av, vb, S1b);
                    S2b = fmaf(av * vb, vb, S2b);
                }
                const float iD = 1.0f / (A + EPSF);
                const float ma = S1a * iD, mb = S1b * iD;
                const float sa = fmaf(-ma, ma, S2a * iD) + EPSF;
                const float sb = fmaf(-mb, mb, S2b * iD) + EPSF;
                dmu_sh[o_m][e0] = ma;
                dmu_sh[o_m][e0 + 1] = mb;
                q_sh[o_m][e0] = 0.5f / sa;
                q_sh[o_m][e0 + 1] = 0.5f / sb;
                float hl = 0.5f * (logf(sa) + logf(sb));
                hl += __shfl_xor(hl, 1, 64);
                hl += __shfl_xor(hl, 2, 64);
                hl += __shfl_xor(hl, 4, 64);
                hl += __shfl_xor(hl, 8, 64);
                hl += __shfl_xor(hl, 16, 64);          // sums within 32-lane o-group
                if (ep == 0) {
                    sumhl_sh[o_m] = hl;
                    const float cost = 64.0f * beta_u[o_m] + A * hl;
                    const float x = LBDF * (beta_a[o_m] - cost);
                    logact_sh[o_m] = logf(1.0f / (1.0f + expf(-x)));
                }
            }
            __syncthreads();                           // B2

            // ---- e-step: all 1024, role (n,o) ----
            const float4* dmu4 = (const float4*)&dmu_sh[o][0];
            const float4* qq4 = (const float4*)&q_sh[o][0];
            const int row = (n << 4) | o;
            const int swz8 = o & 7;
            float acc2 = 0.0f;
            #pragma unroll
            for (int kc = 0; kc < 8; ++kc) {
                const uint4 w = *(const uint4*)(dvb + row * 128 + ((kc ^ swz8) * 16));
                const float4 m0 = dmu4[kc * 2], m1 = dmu4[kc * 2 + 1];
                const float4 q0 = qq4[kc * 2], q1 = qq4[kc * 2 + 1];
                float d;
                d = __uint_as_float(w.x << 16) - m0.x;         acc2 = fmaf(d * d, q0.x, acc2);
                d = __uint_as_float(w.x & 0xFFFF0000u) - m0.y; acc2 = fmaf(d * d, q0.y, acc2);
                d = __uint_as_float(w.y << 16) - m0.z;         acc2 = fmaf(d * d, q0.z, acc2);
                d = __uint_as_float(w.y & 0xFFFF0000u) - m0.w; acc2 = fmaf(d * d, q0.w, acc2);
                d = __uint_as_float(w.z << 16) - m1.x;         acc2 = fmaf(d * d, q1.x, acc2);
                d = __uint_as_float(w.z & 0xFFFF0000u) - m1.y; acc2 = fmaf(d * d, q1.y, acc2);
                d = __uint_as_float(w.w << 16) - m1.z;         acc2 = fmaf(d * d, q1.z, acc2);
                d = __uint_as_float(w.w & 0xFFFF0000u) - m1.w; acc2 = fmaf(d * d, q1.w, acc2);
            }
            float la = -acc2 - sumhl_sh[o] - SUM_LN2PI + logact_sh[o];
            if (msk) la = -10000.0f;
            float mx = la;
            mx = fmaxf(mx, __shfl_xor(mx, 1, 64));
            mx = fmaxf(mx, __shfl_xor(mx, 2, 64));
            mx = fmaxf(mx, __shfl_xor(mx, 4, 64));
            mx = fmaxf(mx, __shfl_xor(mx, 8, 64));
            const float ex = __expf(la - mx);
            float se = ex;
            se += __shfl_xor(se, 1, 64);
            se += __shfl_xor(se, 2, 64);
            se += __shfl_xor(se, 4, 64);
            se += __shfl_xor(se, 8, 64);
            r_loc = ex / se;
        } else {
            // ---- final m-step: mu only ----
            if (tid < 512) {
                const int o_m = tid >> 5;
                const int ep = tid & 31;
                const int e0 = ep * 2;
                const char* dvp0 = dvb + o_m * 128 +
                                   (((e0 >> 3) ^ (o_m & 7)) * 16) + ((e0 & 7) >> 1) * 4;
                float S1a = 0.0f, S1b = 0.0f, A = 0.0f;
                #pragma unroll 8
                for (int nn = 0; nn < NINV; ++nn) {
                    const float av = ar_sh[nn][o_m];
                    const unsigned int w = *(const unsigned int*)(dvp0 + nn * 2048);
                    A += av;
                    S1a = fmaf(av, __uint_as_float(w << 16), S1a);
                    S1b = fmaf(av, __uint_as_float(w & 0xFFFF0000u), S1b);
                }
                const float iD = 1.0f / (A + EPSF);
                const float mu_a = vbar_sh[e0] + S1a * iD;
                const float mu_b = vbar_sh[e0 + 1] + S1b * iD;
                *(float2*)(&out_mu[bl * 1024 + o_m * EE + e0]) = make_float2(mu_a, mu_b);
            }
        }
    }

    out_r[bl * 1024 + tid] = r_loc;    // tid == n*16+o
}

// ---------------------------------------------------------------------------
extern "C" void kernel_launch(void* const* d_in, const int* in_sizes, int n_in,
                              void* d_out, int out_size, void* d_ws, size_t ws_size,
                              hipStream_t stream) {
    const float* inu            = (const float*)d_in[0];
    const unsigned char* mask   = (const unsigned char*)d_in[1];
    const float* ctx            = (const float*)d_in[2];
    const float* rw             = (const float*)d_in[3];
    const float* Wu             = (const float*)d_in[4];
    const float* bu             = (const float*)d_in[5];
    const float* Wc             = (const float*)d_in[6];
    const float* bc             = (const float*)d_in[7];
    const float* Wv             = (const float*)d_in[8];
    const float* bv             = (const float*)d_in[9];
    const float* Wa             = (const float*)d_in[10];
    const float* ba             = (const float*)d_in[11];
    const float* beta_u         = (const float*)d_in[12];
    const float* beta_a         = (const float*)d_in[13];

    float* u_ws    = (float*)d_ws;                    // 524288 f32 (2 MB)
    float* vbar_ws = u_ws + (size_t)BB * NINV * NOUTV * EE;
    float* sc_ws   = vbar_ws + (size_t)BB * LL * EE;  // 16384 f32
    float* a_ws    = sc_ws + (size_t)BB * LL * EE;    // 512 f32
    char*  dv_ws   = (char*)(a_ws + BB * NINV);       // 33.5 MB bf16

    float* out_mu = (float*)d_out;
    float* out_r  = out_mu + (size_t)BB * LL * NOUTV * EE;

    prep_kernel<<<BB * LL + BB, 64, 0, stream>>>(ctx, Wc, bc, inu, Wa, ba, Wv, bv,
                                                 vbar_ws, sc_ws, a_ws);
    priors_u_kernel<<<NINV * NOUTV, 256, 0, stream>>>(inu, rw, Wu, bu, u_ws);
    dv_gemm_kernel<<<2048, 256, 0, stream>>>(u_ws, sc_ws, Wv, dv_ws);
    em_kernel<<<BB * LL, 1024, 0, stream>>>(dv_ws, vbar_ws, a_ws, mask,
                                            beta_u, beta_a, out_mu, out_r);
}

// Round 12
// 51.757 us; speedup vs baseline: 4.0430x; 4.0430x over previous
//
#include <hip/hip_runtime.h>
#include <hip/hip_bf16.h>

// Problem dims (fixed)
#define BB   8
#define LL   32
#define NINV 64
#define NOUTV 16
#define DINV 128
#define EE   64
#define DCV  512

#define EPSF 1e-8f
#define LBDF 1e-3f
// 32 * ln(2*pi)
#define SUM_LN2PI 58.8120661250990508f

// f16 MFMA scaling: A-scale 2^12, B-scale 2^10, descale 2^-22
#define SA_F 4096.0f
#define SB_F 1024.0f
#define DESCALE (1.0f / 4194304.0f)

typedef float f32x4v __attribute__((ext_vector_type(4)));
typedef _Float16 f16x8 __attribute__((ext_vector_type(8)));

static __device__ __forceinline__ unsigned int cvt_pk_bf16(float lo, float hi) {
    unsigned int r;
    asm("v_cvt_pk_bf16_f32 %0, %1, %2" : "=v"(r) : "v"(lo), "v"(hi));
    return r;
}

// ---------------------------------------------------------------------------
// Kernel 1 (blocks 0..255): c = ctx@Wc + bc; tc = tanh(c);
//   vbar[e] = tc @ Wv + bv   (n-independent part of votes, EXACT f32)
//   sc[e]   = 1 - tc^2       (sech^2(c) for the Taylor delta-GEMM)
// (blocks 256..263): actn = sigmoid(inu@Wa + ba)
// ---------------------------------------------------------------------------
__global__ __launch_bounds__(64) void prep_kernel(
    const float* __restrict__ ctx, const float* __restrict__ Wc, const float* __restrict__ bc,
    const float* __restrict__ inu, const float* __restrict__ Wa, const float* __restrict__ ba,
    const float* __restrict__ Wv, const float* __restrict__ bv,
    float* __restrict__ vbar_out, float* __restrict__ sc_out, float* __restrict__ actn_out)
{
    const int blk = blockIdx.x;
    const int t = threadIdx.x;
    __shared__ float row[DCV];
    __shared__ float tc_sh[EE];
    if (blk < BB * LL) {
        const float* cr = ctx + (size_t)blk * DCV;
        #pragma unroll
        for (int i = 0; i < DCV / 64; ++i) row[t + 64 * i] = cr[t + 64 * i];
        __syncthreads();
        float acc = bc[t];
        for (int d = 0; d < DCV; ++d) acc = fmaf(row[d], Wc[d * EE + t], acc);
        const float tc = tanhf(acc);
        tc_sh[t] = tc;
        __syncthreads();
        float vb = bv[t];
        #pragma unroll 8
        for (int e1 = 0; e1 < EE; ++e1) vb = fmaf(tc_sh[e1], Wv[e1 * EE + t], vb);
        vbar_out[blk * EE + t] = vb;
        sc_out[blk * EE + t] = fmaf(-tc, tc, 1.0f);
    } else {
        const int b = blk - BB * LL;
        const float* ir = inu + ((size_t)b * NINV + t) * DINV;
        float acc = ba[0];
        for (int d = 0; d < DINV; ++d) acc = fmaf(ir[d], Wa[d], acc);
        actn_out[b * NINV + t] = 1.0f / (1.0f + expf(-acc));
    }
}

// ---------------------------------------------------------------------------
// Kernel 2: block (n,o):
//   priors[b,e] = sum_d inu[b,n,d] * rw[n,o,d,e]   (8x128 @ 128x64)
//   u[b,n,o,e]  = priors[b,:] @ Wu + bu
// ---------------------------------------------------------------------------
__global__ __launch_bounds__(256) void priors_u_kernel(
    const float* __restrict__ inu, const float* __restrict__ rw,
    const float* __restrict__ Wu, const float* __restrict__ bu,
    float* __restrict__ u_out)
{
    const int no = blockIdx.x;      // n*16+o
    const int n  = no >> 4;
    const int oo = no & 15;
    const int tid = threadIdx.x;

    __shared__ float inu_sh[BB * DINV];   // 4 KB
    __shared__ float pri_sh[BB * EE];     // 2 KB

    {   // stage inu[:, n, :]
        const int b = tid >> 5;
        const int i = (tid & 31) * 4;
        const float4 s = *(const float4*)(inu + ((size_t)b * NINV + n) * DINV + i);
        *(float4*)(inu_sh + b * DINV + i) = s;
    }
    __syncthreads();

    const int bg = tid >> 6;   // 0..3 -> handles b = 2bg, 2bg+1
    const int e  = tid & 63;
    const float* rwp = rw + (size_t)no * DINV * EE + e;
    const float* r0 = inu_sh + (bg * 2) * DINV;
    const float* r1 = inu_sh + (bg * 2 + 1) * DINV;
    float a0 = 0.0f, a1 = 0.0f;
    for (int d = 0; d < DINV; ++d) {
        const float w = rwp[d * EE];
        a0 = fmaf(r0[d], w, a0);
        a1 = fmaf(r1[d], w, a1);
    }
    pri_sh[(bg * 2) * EE + e] = a0;
    pri_sh[(bg * 2 + 1) * EE + e] = a1;
    __syncthreads();

    float b0 = bu[e], b1 = b0;
    const float* p0 = pri_sh + (bg * 2) * EE;
    const float* p1 = pri_sh + (bg * 2 + 1) * EE;
    for (int e1 = 0; e1 < EE; ++e1) {
        const float w = Wu[e1 * EE + e];
        b0 = fmaf(p0[e1], w, b0);
        b1 = fmaf(p1[e1], w, b1);
    }
    u_out[(((size_t)(bg * 2) * NINV + n) * NOUTV + oo) * EE + e] = b0;
    u_out[(((size_t)(bg * 2 + 1) * NINV + n) * NOUTV + oo) * EE + e] = b1;
}

// ---------------------------------------------------------------------------
// Kernel 3 (fused): one 1024-thread block per (b,l).
// Phase A: dv = (U o sc) @ Wv via mfma_f32_16x16x32_f16 with VALUE-converted
// _Float16 fragments (no bit-punning -- round-11's bf16 short-vector builtin
// likely did a silent int->bfloat NUMERIC conversion => garbage => NaN).
// Scaling: A x 2^12, B x 2^10 (both f16-normal range), D x 2^-22.
// Fragment layout (symmetric A/B, m89-verified C/D):
//   A: m=lane&15, k-elems at (lane>>4)*8+i   B: n=lane&15, same k map
//   D: col=lane&15, row=(lane>>4)*4+reg
// (a consistent A/B k-permutation cannot change the dot product).
// Phase B: EM identical to rounds 9/10 (proven); sigma guarded with
// fmaxf(.,0) so any upstream bug gives finite diagnostics, never NaN.
// ---------------------------------------------------------------------------
__global__ __launch_bounds__(1024) void em_fused_kernel(
    const float* __restrict__ u_all, const float* __restrict__ sc_all,
    const float* __restrict__ vbar_all, const float* __restrict__ actn_all,
    const unsigned char* __restrict__ mask_all, const float* __restrict__ Wv,
    const float* __restrict__ beta_u, const float* __restrict__ beta_a,
    float* __restrict__ out_mu, float* __restrict__ out_r)
{
    const int bl = blockIdx.x;           // 0..255  (= b*32 + l)
    const int b = bl >> 5;
    const int tid = threadIdx.x;
    const int n = tid >> 4;              // e-step role
    const int o = tid & 15;
    const int wid = tid >> 6;            // wave 0..15
    const int lane = tid & 63;
    const int l15 = lane & 15;
    const int lk = (lane >> 4) * 8;      // k-offset of this lane's A/B elems

    __shared__ __align__(16) unsigned int dv_sh[NINV * NOUTV * (EE / 2)]; // 128 KB
    __shared__ __align__(16) float dmu_sh[NOUTV][68];
    __shared__ __align__(16) float q_sh[NOUTV][68];
    __shared__ __align__(16) float sc_sh[EE];
    __shared__ float ar_sh[NINV][NOUTV];
    __shared__ float actn_sh[NINV];
    __shared__ float vbar_sh[EE];
    __shared__ float sumhl_sh[NOUTV];
    __shared__ float logact_sh[NOUTV];

    char* dvb = (char*)dv_sh;

    if (tid < EE) sc_sh[tid] = sc_all[bl * EE + tid];
    else if (tid < EE + NINV) actn_sh[tid - EE] = actn_all[b * NINV + (tid - EE)];
    else if (tid < EE + NINV + EE) vbar_sh[tid - EE - NINV] = vbar_all[bl * EE + (tid - EE - NINV)];

    // ---- B-fragments of Wv (f16, value-converted, x2^10): [col-tile][k-half]
    f16x8 bfr[4][2];
    #pragma unroll
    for (int ct = 0; ct < 4; ++ct) {
        #pragma unroll
        for (int kh = 0; kh < 2; ++kh) {
            const float* wp = Wv + (kh * 32 + lk) * EE + ct * 16 + l15;
            f16x8 f;
            f[0] = (_Float16)(wp[0]   * SB_F);
            f[1] = (_Float16)(wp[64]  * SB_F);
            f[2] = (_Float16)(wp[128] * SB_F);
            f[3] = (_Float16)(wp[192] * SB_F);
            f[4] = (_Float16)(wp[256] * SB_F);
            f[5] = (_Float16)(wp[320] * SB_F);
            f[6] = (_Float16)(wp[384] * SB_F);
            f[7] = (_Float16)(wp[448] * SB_F);
            bfr[ct][kh] = f;
        }
    }
    __syncthreads();                                   // sc_sh ready

    // ---- Phase A: MFMA dv GEMM -> swizzled bf16 LDS ----
    {
        // pre-scaled sech^2 factors for this lane's k-slots
        float sA0[8], sA1[8];
        #pragma unroll
        for (int i = 0; i < 8; ++i) {
            sA0[i] = sc_sh[lk + i] * SA_F;
            sA1[i] = sc_sh[32 + lk + i] * SA_F;
        }
        const float* urow = u_all + ((size_t)b * 1024 + wid * 64 + l15) * EE;
        #pragma unroll
        for (int rt = 0; rt < 4; ++rt) {
            const float* up = urow + rt * 16 * EE;
            const float4 ul0 = *(const float4*)(up + lk);
            const float4 uh0 = *(const float4*)(up + lk + 4);
            const float4 ul1 = *(const float4*)(up + 32 + lk);
            const float4 uh1 = *(const float4*)(up + 32 + lk + 4);
            f16x8 a0, a1;
            a0[0] = (_Float16)(ul0.x * sA0[0]);
            a0[1] = (_Float16)(ul0.y * sA0[1]);
            a0[2] = (_Float16)(ul0.z * sA0[2]);
            a0[3] = (_Float16)(ul0.w * sA0[3]);
            a0[4] = (_Float16)(uh0.x * sA0[4]);
            a0[5] = (_Float16)(uh0.y * sA0[5]);
            a0[6] = (_Float16)(uh0.z * sA0[6]);
            a0[7] = (_Float16)(uh0.w * sA0[7]);
            a1[0] = (_Float16)(ul1.x * sA1[0]);
            a1[1] = (_Float16)(ul1.y * sA1[1]);
            a1[2] = (_Float16)(ul1.z * sA1[2]);
            a1[3] = (_Float16)(ul1.w * sA1[3]);
            a1[4] = (_Float16)(uh1.x * sA1[4]);
            a1[5] = (_Float16)(uh1.y * sA1[5]);
            a1[6] = (_Float16)(uh1.z * sA1[6]);
            a1[7] = (_Float16)(uh1.w * sA1[7]);
            #pragma unroll
            for (int ct = 0; ct < 4; ++ct) {
                f32x4v acc = {0.0f, 0.0f, 0.0f, 0.0f};
                acc = __builtin_amdgcn_mfma_f32_16x16x32_f16(a0, bfr[ct][0], acc, 0, 0, 0);
                acc = __builtin_amdgcn_mfma_f32_16x16x32_f16(a1, bfr[ct][1], acc, 0, 0, 0);
                const int col = ct * 16 + l15;
                const int kc = col >> 3;
                const int cb = (col & 7) << 1;
                #pragma unroll
                for (int j = 0; j < 4; ++j) {
                    const float dvj = acc[j] * DESCALE;
                    const int row = wid * 64 + rt * 16 + (lane >> 4) * 4 + j;
                    const int addr = row * 128 + ((kc ^ (row & 7)) << 4) + cb;
                    *(unsigned short*)(dvb + addr) =
                        (unsigned short)cvt_pk_bf16(dvj, dvj);
                }
            }
        }
    }
    __syncthreads();                                   // dv ready

    const unsigned char msk = mask_all[b * NINV + n];
    float r_loc = 1.0f / 16.0f;

    for (int it = 0; it < 3; ++it) {
        // ---- ar (normalized over o), write to LDS ----
        float arv = actn_sh[n] * r_loc;
        float s = arv;
        s += __shfl_xor(s, 1, 64);
        s += __shfl_xor(s, 2, 64);
        s += __shfl_xor(s, 4, 64);
        s += __shfl_xor(s, 8, 64);
        arv = arv / (s + EPSF);
        ar_sh[n][o] = arv;
        __syncthreads();                               // B1

        if (it < 2) {
            // ---- m-pass: 512 threads, role (o_m, e-pair); sum over n ----
            if (tid < 512) {
                const int o_m = tid >> 5;
                const int ep = tid & 31;
                const int e0 = ep * 2;
                const char* dvp0 = dvb + o_m * 128 +
                                   (((e0 >> 3) ^ (o_m & 7)) * 16) + ((e0 & 7) >> 1) * 4;
                float S1a = 0.0f, S2a = 0.0f, S1b = 0.0f, S2b = 0.0f, A = 0.0f;
                #pragma unroll 8
                for (int nn = 0; nn < NINV; ++nn) {
                    const float av = ar_sh[nn][o_m];
                    const unsigned int w = *(const unsigned int*)(dvp0 + nn * 2048);
                    const float va = __uint_as_float(w << 16);
                    const float vb = __uint_as_float(w & 0xFFFF0000u);
                    A += av;
                    S1a = fmaf(av, va, S1a);
                    S2a = fmaf(av * va, va, S2a);
                    S1b = fmaf(av, vb, S1b);
                    S2b = fmaf(av * vb, vb, S2b);
                }
                const float iD = 1.0f / (A + EPSF);
                const float ma = S1a * iD, mb = S1b * iD;
                const float sa = fmaxf(fmaf(-ma, ma, S2a * iD), 0.0f) + EPSF;
                const float sb = fmaxf(fmaf(-mb, mb, S2b * iD), 0.0f) + EPSF;
                dmu_sh[o_m][e0] = ma;
                dmu_sh[o_m][e0 + 1] = mb;
                q_sh[o_m][e0] = 0.5f / sa;
                q_sh[o_m][e0 + 1] = 0.5f / sb;
                float hl = 0.5f * (logf(sa) + logf(sb));
                hl += __shfl_xor(hl, 1, 64);
                hl += __shfl_xor(hl, 2, 64);
                hl += __shfl_xor(hl, 4, 64);
                hl += __shfl_xor(hl, 8, 64);
                hl += __shfl_xor(hl, 16, 64);          // sums within 32-lane o-group
                if (ep == 0) {
                    sumhl_sh[o_m] = hl;
                    const float cost = 64.0f * beta_u[o_m] + A * hl;
                    const float x = LBDF * (beta_a[o_m] - cost);
                    logact_sh[o_m] = logf(1.0f / (1.0f + expf(-x)));
                }
            }
            __syncthreads();                           // B2

            // ---- e-step: all 1024, role (n,o) ----
            const float4* dmu4 = (const float4*)&dmu_sh[o][0];
            const float4* qq4 = (const float4*)&q_sh[o][0];
            const int row = (n << 4) | o;
            const int swz8 = o & 7;
            float acc2 = 0.0f;
            #pragma unroll
            for (int kc = 0; kc < 8; ++kc) {
                const uint4 w = *(const uint4*)(dvb + row * 128 + ((kc ^ swz8) * 16));
                const float4 m0 = dmu4[kc * 2], m1 = dmu4[kc * 2 + 1];
                const float4 q0 = qq4[kc * 2], q1 = qq4[kc * 2 + 1];
                float d;
                d = __uint_as_float(w.x << 16) - m0.x;         acc2 = fmaf(d * d, q0.x, acc2);
                d = __uint_as_float(w.x & 0xFFFF0000u) - m0.y; acc2 = fmaf(d * d, q0.y, acc2);
                d = __uint_as_float(w.y << 16) - m0.z;         acc2 = fmaf(d * d, q0.z, acc2);
                d = __uint_as_float(w.y & 0xFFFF0000u) - m0.w; acc2 = fmaf(d * d, q0.w, acc2);
                d = __uint_as_float(w.z << 16) - m1.x;         acc2 = fmaf(d * d, q1.x, acc2);
                d = __uint_as_float(w.z & 0xFFFF0000u) - m1.y; acc2 = fmaf(d * d, q1.y, acc2);
                d = __uint_as_float(w.w << 16) - m1.z;         acc2 = fmaf(d * d, q1.z, acc2);
                d = __uint_as_float(w.w & 0xFFFF0000u) - m1.w; acc2 = fmaf(d * d, q1.w, acc2);
            }
            float la = -acc2 - sumhl_sh[o] - SUM_LN2PI + logact_sh[o];
            if (msk) la = -10000.0f;
            float mx = la;
            mx = fmaxf(mx, __shfl_xor(mx, 1, 64));
            mx = fmaxf(mx, __shfl_xor(mx, 2, 64));
            mx = fmaxf(mx, __shfl_xor(mx, 4, 64));
            mx = fmaxf(mx, __shfl_xor(mx, 8, 64));
            const float ex = __expf(la - mx);
            float se = ex;
            se += __shfl_xor(se, 1, 64);
            se += __shfl_xor(se, 2, 64);
            se += __shfl_xor(se, 4, 64);
            se += __shfl_xor(se, 8, 64);
            r_loc = ex / se;
        } else {
            // ---- final m-step: mu only ----
            if (tid < 512) {
                const int o_m = tid >> 5;
                const int ep = tid & 31;
                const int e0 = ep * 2;
                const char* dvp0 = dvb + o_m * 128 +
                                   (((e0 >> 3) ^ (o_m & 7)) * 16) + ((e0 & 7) >> 1) * 4;
                float S1a = 0.0f, S1b = 0.0f, A = 0.0f;
                #pragma unroll 8
                for (int nn = 0; nn < NINV; ++nn) {
                    const float av = ar_sh[nn][o_m];
                    const unsigned int w = *(const unsigned int*)(dvp0 + nn * 2048);
                    A += av;
                    S1a = fmaf(av, __uint_as_float(w << 16), S1a);
                    S1b = fmaf(av, __uint_as_float(w & 0xFFFF0000u), S1b);
                }
                const float iD = 1.0f / (A + EPSF);
                const float mu_a = vbar_sh[e0] + S1a * iD;
                const float mu_b = vbar_sh[e0 + 1] + S1b * iD;
                *(float2*)(&out_mu[bl * 1024 + o_m * EE + e0]) = make_float2(mu_a, mu_b);
            }
        }
    }

    out_r[bl * 1024 + tid] = r_loc;    // tid == n*16+o
}

// ---------------------------------------------------------------------------
extern "C" void kernel_launch(void* const* d_in, const int* in_sizes, int n_in,
                              void* d_out, int out_size, void* d_ws, size_t ws_size,
                              hipStream_t stream) {
    const float* inu            = (const float*)d_in[0];
    const unsigned char* mask   = (const unsigned char*)d_in[1];
    const float* ctx            = (const float*)d_in[2];
    const float* rw             = (const float*)d_in[3];
    const float* Wu             = (const float*)d_in[4];
    const float* bu             = (const float*)d_in[5];
    const float* Wc             = (const float*)d_in[6];
    const float* bc             = (const float*)d_in[7];
    const float* Wv             = (const float*)d_in[8];
    const float* bv             = (const float*)d_in[9];
    const float* Wa             = (const float*)d_in[10];
    const float* ba             = (const float*)d_in[11];
    const float* beta_u         = (const float*)d_in[12];
    const float* beta_a         = (const float*)d_in[13];

    float* u_ws    = (float*)d_ws;                    // 524288 f32 (2 MB)
    float* vbar_ws = u_ws + (size_t)BB * NINV * NOUTV * EE;
    float* sc_ws   = vbar_ws + (size_t)BB * LL * EE;  // 16384 f32
    float* a_ws    = sc_ws + (size_t)BB * LL * EE;    // 512 f32

    float* out_mu = (float*)d_out;
    float* out_r  = out_mu + (size_t)BB * LL * NOUTV * EE;

    prep_kernel<<<BB * LL + BB, 64, 0, stream>>>(ctx, Wc, bc, inu, Wa, ba, Wv, bv,
                                                 vbar_ws, sc_ws, a_ws);
    priors_u_kernel<<<NINV * NOUTV, 256, 0, stream>>>(inu, rw, Wu, bu, u_ws);
    em_fused_kernel<<<BB * LL, 1024, 0, stream>>>(u_ws, sc_ws, vbar_ws, a_ws, mask, Wv,
                                                  beta_u, beta_a, out_mu, out_r);
}

// Round 14
// 43.377 us; speedup vs baseline: 4.8239x; 1.1932x over previous
//
#include <hip/hip_runtime.h>
#include <hip/hip_bf16.h>

// Problem dims (fixed)
#define BB   8
#define LL   32
#define NINV 64
#define NOUTV 16
#define DINV 128
#define EE   64
#define DCV  512

#define EPSF 1e-8f
#define LBDF 1e-3f
// 32 * ln(2*pi)
#define SUM_LN2PI 58.8120661250990508f

// f16 MFMA scaling: A(u) x 2^12, B(sc*Wv) x 2^10, descale 2^-22
#define SA_F 4096.0f
#define SB_F 1024.0f
#define DESCALE (1.0f / 4194304.0f)

typedef float f32x4v __attribute__((ext_vector_type(4)));
typedef _Float16 f16x8 __attribute__((ext_vector_type(8)));
typedef __fp16 fp16x2 __attribute__((ext_vector_type(2)));

union pk16 { fp16x2 h; unsigned int u; };

static __device__ __forceinline__ unsigned int cvt_pk_bf16(float lo, float hi) {
    unsigned int r;
    asm("v_cvt_pk_bf16_f32 %0, %1, %2" : "=v"(r) : "v"(lo), "v"(hi));
    return r;
}

// ---------------------------------------------------------------------------
// Kernel 1 (merged front-end), 1288 blocks x 256:
//  blk <  1024: priors[b,e]=inu[b,n,:]@rw[n,o,:,e]; u=priors@Wu+bu -> f16 x2^12
//  1024..1279:  bl=blk-1024: c=ctx@Wc+bc (4-way d-split); tc=tanh(c);
//               vbar = tc@Wv+bv (exact f32); scWv[bl][n][k] = sc[k]*Wv[k][n]
//               as f16 x2^10, k-contiguous (the em B-fragment, precomputed)
//  1280..1287:  actn = sigmoid(inu@Wa+ba)
// Merging gives prep's latency chains TLP cover from the HBM-bound priors
// blocks (round-12: prep alone = 1 wave/CU, zero TLP).
// ---------------------------------------------------------------------------
__global__ __launch_bounds__(256) void pre_kernel(
    const float* __restrict__ inu, const float* __restrict__ rw,
    const float* __restrict__ Wu, const float* __restrict__ bu,
    const float* __restrict__ ctx, const float* __restrict__ Wc, const float* __restrict__ bc,
    const float* __restrict__ Wv, const float* __restrict__ bv,
    const float* __restrict__ Wa, const float* __restrict__ ba,
    _Float16* __restrict__ u16, _Float16* __restrict__ scwv,
    float* __restrict__ vbar_out, float* __restrict__ actn_out)
{
    const int blk = blockIdx.x;
    const int tid = threadIdx.x;
    __shared__ float sh_a[BB * DINV];     // priors: inu_sh | prep: ctx row(512)+part(256)
    __shared__ float sh_b[BB * EE];       // priors: pri_sh | prep: tc_sh

    if (blk < NINV * NOUTV) {
        // ---------------- priors + u (f16) ----------------
        const int n  = blk >> 4;
        {   // stage inu[:, n, :]
            const int b = tid >> 5;
            const int i = (tid & 31) * 4;
            const float4 s = *(const float4*)(inu + ((size_t)b * NINV + n) * DINV + i);
            *(float4*)(sh_a + b * DINV + i) = s;
        }
        __syncthreads();

        {   // GEMM1: thread (bg,e) handles b=2bg,2bg+1
            const int bg = tid >> 6;
            const int e  = tid & 63;
            const float* rwp = rw + (size_t)blk * DINV * EE + e;
            const float* r0 = sh_a + (bg * 2) * DINV;
            const float* r1 = sh_a + (bg * 2 + 1) * DINV;
            float a0 = 0.0f, a1 = 0.0f;
            for (int d = 0; d < DINV; ++d) {
                const float w = rwp[d * EE];
                a0 = fmaf(r0[d], w, a0);
                a1 = fmaf(r1[d], w, a1);
            }
            sh_b[(bg * 2) * EE + e] = a0;
            sh_b[(bg * 2 + 1) * EE + e] = a1;
        }
        __syncthreads();

        // GEMM2: thread (bq, e-pair); u -> f16 x 2^12, coalesced dwords
        const int bq = tid >> 5;
        const int e0 = (tid & 31) * 2;
        float b0 = bu[e0], b1 = bu[e0 + 1];
        const float* p = sh_b + bq * EE;
        for (int e1 = 0; e1 < EE; ++e1) {
            const float2 w = *(const float2*)&Wu[e1 * EE + e0];
            b0 = fmaf(p[e1], w.x, b0);
            b1 = fmaf(p[e1], w.y, b1);
        }
        pk16 pk;
        pk.h = __builtin_amdgcn_cvt_pkrtz(b0 * SA_F, b1 * SA_F);
        *(unsigned int*)((char*)u16 + (((size_t)bq * 1024 + blk) * EE + e0) * 2) = pk.u;

    } else if (blk < NINV * NOUTV + BB * LL) {
        // ---------------- prep-c: c, vbar, scWv ----------------
        const int bl = blk - NINV * NOUTV;
        const float* cr = ctx + (size_t)bl * DCV;
        // stage ctx row (512 floats, 256 threads x 2)
        sh_a[tid] = cr[tid];
        sh_a[tid + 256] = cr[tid + 256];
        __syncthreads();
        // c GEMM, 4-way d-split: thread (q=tid>>6, e=tid&63)
        {
            const int q = tid >> 6;
            const int e = tid & 63;
            const float* rp = sh_a + q * 128;
            const float* wp = Wc + (q * 128) * EE + e;
            float acc = 0.0f;
            for (int d = 0; d < 128; ++d) acc = fmaf(rp[d], wp[d * EE], acc);
            sh_a[512 + q * 64 + e] = acc;   // partials after the row data
        }
        __syncthreads();
        if (tid < EE) {
            const float c = sh_a[512 + tid] + sh_a[576 + tid] + sh_a[640 + tid]
                          + sh_a[704 + tid] + bc[tid];
            sh_b[tid] = tanhf(c);
        }
        __syncthreads();
        if (tid < EE) {
            const int t = tid;
            float vb = bv[t];
            pk16 scw[32];
            #pragma unroll
            for (int e2 = 0; e2 < 32; ++e2) {
                const float t0 = sh_b[2 * e2], t1 = sh_b[2 * e2 + 1];
                const float w0 = Wv[(2 * e2) * EE + t];
                const float w1 = Wv[(2 * e2 + 1) * EE + t];
                vb = fmaf(t0, w0, fmaf(t1, w1, vb));
                const float s0 = fmaf(-t0, t0, 1.0f) * w0 * SB_F;
                const float s1 = fmaf(-t1, t1, 1.0f) * w1 * SB_F;
                scw[e2].h = __builtin_amdgcn_cvt_pkrtz(s0, s1);
            }
            vbar_out[bl * EE + t] = vb;
            uint4* dst = (uint4*)((char*)scwv + ((size_t)bl * EE + t) * EE * 2);
            #pragma unroll
            for (int q = 0; q < 8; ++q) {
                uint4 v;
                v.x = scw[q * 4 + 0].u;
                v.y = scw[q * 4 + 1].u;
                v.z = scw[q * 4 + 2].u;
                v.w = scw[q * 4 + 3].u;
                dst[q] = v;
            }
        }
    } else {
        // ---------------- actn ----------------
        const int b = blk - (NINV * NOUTV + BB * LL);
        if (tid < NINV) {
            const float* ir = inu + ((size_t)b * NINV + tid) * DINV;
            float acc = ba[0];
            for (int d = 0; d < DINV; ++d) acc = fmaf(ir[d], Wa[d], acc);
            actn_out[b * NINV + tid] = 1.0f / (1.0f + expf(-acc));
        }
    }
}

// ---------------------------------------------------------------------------
// Kernel 2 (fused): one 1024-thread block per (b,l).
// Phase A: dv = u16 @ scWv[bl] via mfma_f32_16x16x32_f16. ALL fragments are
// now direct 16-B loads (A from u16, B from scWv) -- zero convert/mul VALU
// (round-12 spent ~400 VALU/wave building fragments inline).
// Layout (R12-proven): A m=lane&15,k=(lane>>4)*8+i; B n=lane&15,same k;
// D col=lane&15,row=(lane>>4)*4+reg. D x2^-22 -> bf16 -> swizzled LDS.
// Phase B: EM identical to rounds 9/10/12 (proven).
// ---------------------------------------------------------------------------
__global__ __launch_bounds__(1024) void em_fused_kernel(
    const _Float16* __restrict__ u16, const _Float16* __restrict__ scwv,
    const float* __restrict__ vbar_all, const float* __restrict__ actn_all,
    const unsigned char* __restrict__ mask_all,
    const float* __restrict__ beta_u, const float* __restrict__ beta_a,
    float* __restrict__ out_mu, float* __restrict__ out_r)
{
    const int bl = blockIdx.x;           // 0..255  (= b*32 + l)
    const int b = bl >> 5;
    const int tid = threadIdx.x;
    const int n = tid >> 4;              // e-step role
    const int o = tid & 15;
    const int wid = tid >> 6;            // wave 0..15
    const int lane = tid & 63;
    const int l15 = lane & 15;
    const int lk = (lane >> 4) * 8;      // k-offset of this lane's A/B elems

    __shared__ __align__(16) unsigned int dv_sh[NINV * NOUTV * (EE / 2)]; // 128 KB
    __shared__ __align__(16) float dmu_sh[NOUTV][68];
    __shared__ __align__(16) float q_sh[NOUTV][68];
    __shared__ float ar_sh[NINV][NOUTV];
    __shared__ float actn_sh[NINV];
    __shared__ float vbar_sh[EE];
    __shared__ float sumhl_sh[NOUTV];
    __shared__ float logact_sh[NOUTV];

    char* dvb = (char*)dv_sh;

    if (tid < NINV) actn_sh[tid] = actn_all[b * NINV + tid];
    else if (tid < NINV + EE) vbar_sh[tid - NINV] = vbar_all[bl * EE + (tid - NINV)];

    // ---- B-fragments: direct 16-B loads from precomputed scWv[bl] ----
    f16x8 bfr[4][2];
    #pragma unroll
    for (int ct = 0; ct < 4; ++ct) {
        #pragma unroll
        for (int kh = 0; kh < 2; ++kh) {
            bfr[ct][kh] = *(const f16x8*)((const char*)scwv +
                (((size_t)bl * EE + (ct * 16 + l15)) * EE + kh * 32 + lk) * 2);
        }
    }

    // ---- Phase A: MFMA dv GEMM -> swizzled bf16 LDS ----
    {
        const char* urow = (const char*)u16 +
            ((size_t)b * 1024 + wid * 64 + l15) * EE * 2;
        #pragma unroll
        for (int rt = 0; rt < 4; ++rt) {
            const char* up = urow + (size_t)rt * 16 * EE * 2;
            const f16x8 a0 = *(const f16x8*)(up + lk * 2);
            const f16x8 a1 = *(const f16x8*)(up + 64 + lk * 2);
            #pragma unroll
            for (int ct = 0; ct < 4; ++ct) {
                f32x4v acc = {0.0f, 0.0f, 0.0f, 0.0f};
                acc = __builtin_amdgcn_mfma_f32_16x16x32_f16(a0, bfr[ct][0], acc, 0, 0, 0);
                acc = __builtin_amdgcn_mfma_f32_16x16x32_f16(a1, bfr[ct][1], acc, 0, 0, 0);
                const int col = ct * 16 + l15;
                const int kc = col >> 3;
                const int cb = (col & 7) << 1;
                #pragma unroll
                for (int j = 0; j < 4; ++j) {
                    const float dvj = acc[j] * DESCALE;
                    const int row = wid * 64 + rt * 16 + (lane >> 4) * 4 + j;
                    const int addr = row * 128 + ((kc ^ (row & 7)) << 4) + cb;
                    *(unsigned short*)(dvb + addr) =
                        (unsigned short)cvt_pk_bf16(dvj, dvj);
                }
            }
        }
    }
    __syncthreads();                                   // dv + staging ready

    const unsigned char msk = mask_all[b * NINV + n];
    float r_loc = 1.0f / 16.0f;

    for (int it = 0; it < 3; ++it) {
        // ---- ar (normalized over o), write to LDS ----
        float arv = actn_sh[n] * r_loc;
        float s = arv;
        s += __shfl_xor(s, 1, 64);
        s += __shfl_xor(s, 2, 64);
        s += __shfl_xor(s, 4, 64);
        s += __shfl_xor(s, 8, 64);
        arv = arv / (s + EPSF);
        ar_sh[n][o] = arv;
        __syncthreads();                               // B1

        if (it < 2) {
            // ---- m-pass: 512 threads, role (o_m, e-pair); sum over n ----
            if (tid < 512) {
                const int o_m = tid >> 5;
                const int ep = tid & 31;
                const int e0 = ep * 2;
                const char* dvp0 = dvb + o_m * 128 +
                                   (((e0 >> 3) ^ (o_m & 7)) * 16) + ((e0 & 7) >> 1) * 4;
                float S1a = 0.0f, S2a = 0.0f, S1b = 0.0f, S2b = 0.0f, A = 0.0f;
                #pragma unroll 8
                for (int nn = 0; nn < NINV; ++nn) {
                    const float av = ar_sh[nn][o_m];
                    const unsigned int w = *(const unsigned int*)(dvp0 + nn * 2048);
                    const float va = __uint_as_float(w << 16);
                    const float vb = __uint_as_float(w & 0xFFFF0000u);
                    A += av;
                    S1a = fmaf(av, va, S1a);
                    S2a = fmaf(av * va, va, S2a);
                    S1b = fmaf(av, vb, S1b);
                    S2b = fmaf(av * vb, vb, S2b);
                }
                const float iD = 1.0f / (A + EPSF);
                const float ma = S1a * iD, mb = S1b * iD;
                const float sa = fmaxf(fmaf(-ma, ma, S2a * iD), 0.0f) + EPSF;
                const float sb = fmaxf(fmaf(-mb, mb, S2b * iD), 0.0f) + EPSF;
                dmu_sh[o_m][e0] = ma;
                dmu_sh[o_m][e0 + 1] = mb;
                q_sh[o_m][e0] = 0.5f / sa;
                q_sh[o_m][e0 + 1] = 0.5f / sb;
                float hl = 0.5f * (logf(sa) + logf(sb));
                hl += __shfl_xor(hl, 1, 64);
                hl += __shfl_xor(hl, 2, 64);
                hl += __shfl_xor(hl, 4, 64);
                hl += __shfl_xor(hl, 8, 64);
                hl += __shfl_xor(hl, 16, 64);          // sums within 32-lane o-group
                if (ep == 0) {
                    sumhl_sh[o_m] = hl;
                    const float cost = 64.0f * beta_u[o_m] + A * hl;
                    const float x = LBDF * (beta_a[o_m] - cost);
                    logact_sh[o_m] = logf(1.0f / (1.0f + expf(-x)));
                }
            }
            __syncthreads();                           // B2

            // ---- e-step: all 1024, role (n,o) ----
            const float4* dmu4 = (const float4*)&dmu_sh[o][0];
            const float4* qq4 = (const float4*)&q_sh[o][0];
            const int row = (n << 4) | o;
            const int swz8 = o & 7;
            float acc2 = 0.0f;
            #pragma unroll
            for (int kc = 0; kc < 8; ++kc) {
                const uint4 w = *(const uint4*)(dvb + row * 128 + ((kc ^ swz8) * 16));
                const float4 m0 = dmu4[kc * 2], m1 = dmu4[kc * 2 + 1];
                const float4 q0 = qq4[kc * 2], q1 = qq4[kc * 2 + 1];
                float d;
                d = __uint_as_float(w.x << 16) - m0.x;         acc2 = fmaf(d * d, q0.x, acc2);
                d = __uint_as_float(w.x & 0xFFFF0000u) - m0.y; acc2 = fmaf(d * d, q0.y, acc2);
                d = __uint_as_float(w.y << 16) - m0.z;         acc2 = fmaf(d * d, q0.z, acc2);
                d = __uint_as_float(w.y & 0xFFFF0000u) - m0.w; acc2 = fmaf(d * d, q0.w, acc2);
                d = __uint_as_float(w.z << 16) - m1.x;         acc2 = fmaf(d * d, q1.x, acc2);
                d = __uint_as_float(w.z & 0xFFFF0000u) - m1.y; acc2 = fmaf(d * d, q1.y, acc2);
                d = __uint_as_float(w.w << 16) - m1.z;         acc2 = fmaf(d * d, q1.z, acc2);
                d = __uint_as_float(w.w & 0xFFFF0000u) - m1.w; acc2 = fmaf(d * d, q1.w, acc2);
            }
            float la = -acc2 - sumhl_sh[o] - SUM_LN2PI + logact_sh[o];
            if (msk) la = -10000.0f;
            float mx = la;
            mx = fmaxf(mx, __shfl_xor(mx, 1, 64));
            mx = fmaxf(mx, __shfl_xor(mx, 2, 64));
            mx = fmaxf(mx, __shfl_xor(mx, 4, 64));
            mx = fmaxf(mx, __shfl_xor(mx, 8, 64));
            const float ex = __expf(la - mx);
            float se = ex;
            se += __shfl_xor(se, 1, 64);
            se += __shfl_xor(se, 2, 64);
            se += __shfl_xor(se, 4, 64);
            se += __shfl_xor(se, 8, 64);
            r_loc = ex / se;
        } else {
            // ---- final m-step: mu only ----
            if (tid < 512) {
                const int o_m = tid >> 5;
                const int ep = tid & 31;
                const int e0 = ep * 2;
                const char* dvp0 = dvb + o_m * 128 +
                                   (((e0 >> 3) ^ (o_m & 7)) * 16) + ((e0 & 7) >> 1) * 4;
                float S1a = 0.0f, S1b = 0.0f, A = 0.0f;
                #pragma unroll 8
                for (int nn = 0; nn < NINV; ++nn) {
                    const float av = ar_sh[nn][o_m];
                    const unsigned int w = *(const unsigned int*)(dvp0 + nn * 2048);
                    A += av;
                    S1a = fmaf(av, __uint_as_float(w << 16), S1a);
                    S1b = fmaf(av, __uint_as_float(w & 0xFFFF0000u), S1b);
                }
                const float iD = 1.0f / (A + EPSF);
                const float mu_a = vbar_sh[e0] + S1a * iD;
                const float mu_b = vbar_sh[e0 + 1] + S1b * iD;
                *(float2*)(&out_mu[bl * 1024 + o_m * EE + e0]) = make_float2(mu_a, mu_b);
            }
        }
    }

    out_r[bl * 1024 + tid] = r_loc;    // tid == n*16+o
}

// ---------------------------------------------------------------------------
extern "C" void kernel_launch(void* const* d_in, const int* in_sizes, int n_in,
                              void* d_out, int out_size, void* d_ws, size_t ws_size,
                              hipStream_t stream) {
    const float* inu            = (const float*)d_in[0];
    const unsigned char* mask   = (const unsigned char*)d_in[1];
    const float* ctx            = (const float*)d_in[2];
    const float* rw             = (const float*)d_in[3];
    const float* Wu             = (const float*)d_in[4];
    const float* bu             = (const float*)d_in[5];
    const float* Wc             = (const float*)d_in[6];
    const float* bc             = (const float*)d_in[7];
    const float* Wv             = (const float*)d_in[8];
    const float* bv             = (const float*)d_in[9];
    const float* Wa             = (const float*)d_in[10];
    const float* ba             = (const float*)d_in[11];
    const float* beta_u         = (const float*)d_in[12];
    const float* beta_a         = (const float*)d_in[13];

    _Float16* scwv = (_Float16*)d_ws;                         // 2 MB
    _Float16* u16  = scwv + (size_t)BB * LL * EE * EE;        // 1 MB
    float* vbar_ws = (float*)(u16 + (size_t)BB * 1024 * EE);  // 64 KB
    float* a_ws    = vbar_ws + (size_t)BB * LL * EE;          // 2 KB

    float* out_mu = (float*)d_out;
    float* out_r  = out_mu + (size_t)BB * LL * NOUTV * EE;

    pre_kernel<<<NINV * NOUTV + BB * LL + BB, 256, 0, stream>>>(
        inu, rw, Wu, bu, ctx, Wc, bc, Wv, bv, Wa, ba,
        u16, scwv, vbar_ws, a_ws);
    em_fused_kernel<<<BB * LL, 1024, 0, stream>>>(u16, scwv, vbar_ws, a_ws, mask,
                                                  beta_u, beta_a, out_mu, out_r);
}